// Round 9
// baseline (21129.471 us; speedup 1.0000x reference)
//
#include <hip/hip_runtime.h>
#include <hip/hip_bf16.h>
#include <stdint.h>

#define T_LEN 1000
#define KIN   69
#define KIN_P 96
#define G3    1536
#define HDIM  512
#define POLL_MAX 30000
#define SENT 0xFFFFFFFFu   // bf16 NaN|NaN — unreachable for GRU h in (-1,1)

typedef __attribute__((ext_vector_type(8))) short short8;
typedef __attribute__((ext_vector_type(4))) float f32x4;

#define MFMA(a,b,c) __builtin_amdgcn_mfma_f32_16x16x32_bf16((a),(b),(c),0,0,0)
#define AGENT __HIP_MEMORY_SCOPE_AGENT

static __device__ __forceinline__ float sigm(float x){ return 1.0f/(1.0f+__expf(-x)); }
static __device__ __forceinline__ float tanh_f(float x){
  float a = fabsf(x);
  float e = __expf(2.0f*a);
  float t = 1.0f - 2.0f/(e+1.0f);
  return x >= 0.0f ? t : -t;
}
static __device__ __forceinline__ unsigned short f2bf(float f){
  union { float f; unsigned int u; } v; v.f = f;
  unsigned int u = v.u;
  return (unsigned short)((u + 0x7fffu + ((u>>16)&1u)) >> 16);   // RNE
}

// ---------------- small converters ----------------
__global__ void k_conv(const float* __restrict__ src, unsigned short* __restrict__ dst, int n){
  int i = blockIdx.x*256 + threadIdx.x;
  if (i < n) dst[i] = f2bf(src[i]);
}
__global__ void k_conv_pad(const float* __restrict__ src, unsigned short* __restrict__ dst,
                           int rows, int ks, int kd){
  int i = blockIdx.x*256 + threadIdx.x;
  int r = i / kd, c = i % kd;
  if (r < rows) dst[i] = (c < ks) ? f2bf(src[r*ks + c]) : (unsigned short)0;
}
__global__ void k_sentinel(float* __restrict__ out, int n){
  int i = blockIdx.x*256 + threadIdx.x;
  if (i < n) out[i] = 1234.5f;
}

// x: [64][69][1000] f32  ->  xT: [(t*64+b)][96] bf16
__global__ void k_xpose(const float* __restrict__ x, unsigned short* __restrict__ xT){
  int b = blockIdx.x & 63, tt = blockIdx.x >> 6;
  int t = tt*64 + threadIdx.x;
  if (t >= T_LEN) return;
  unsigned int* dst = (unsigned int*)(xT + (size_t)(t*64+b)*KIN_P);
  #pragma unroll
  for (int i=0;i<48;i++){
    int k0 = 2*i, k1 = 2*i+1;
    unsigned int lo = (k0<KIN) ? f2bf(x[((size_t)b*KIN + k0)*T_LEN + t]) : 0u;
    unsigned int hi = (k1<KIN) ? f2bf(x[((size_t)b*KIN + k1)*T_LEN + t]) : 0u;
    dst[i] = lo | (hi<<16);
  }
}

// ---------------- layer 0: fused input-proj + bidirectional recurrence ----------------
// grid = 32 blocks: dir = bid/16, slice n = bid%16 owns gate cols j in [32n, 32n+32)
// h exchange: 3-slot sentinel ring; INCREMENTAL chunk consume (poll->MFMA per 32-col chunk).
#define NB_B 16
__launch_bounds__(512)
__global__ void k_gru0(const unsigned short* __restrict__ xT,
                       const unsigned short* __restrict__ whh0,
                       const unsigned short* __restrict__ wih0,
                       const float* __restrict__ bih_f, const float* __restrict__ bhh_f,
                       const float* __restrict__ bih_b, const float* __restrict__ bhh_b,
                       unsigned short* __restrict__ l0out,
                       unsigned int* __restrict__ hbuf)   // [2][3][64][256] dwords
{
  int bid = blockIdx.x;
  int dir = bid / NB_B;
  int n   = bid % NB_B;
  int j0  = n*32;
  int tid = threadIdx.x;
  int w = tid>>6, l = tid&63;
  int m0  = (w & 3) * 16;
  int h16 = w >> 2;
  int lj = l & 15, lg = l >> 4;

  __shared__ unsigned char lds[96*1024 + 96*192];
  unsigned char* whh_lds = lds;
  unsigned char* wih_lds = lds + 96*1024;
  const unsigned short* whh_g = whh0 + (size_t)dir*G3*HDIM;
  const unsigned short* wih_g = wih0 + (size_t)dir*G3*KIN_P;

  for (int c = tid; c < 96*64; c += 512){
    int lr = c >> 6, c16 = c & 63;
    int g = lr >> 5, jl = lr & 31;
    int gr = g*512 + j0 + jl;
    uint4 v = *(const uint4*)(whh_g + (size_t)gr*HDIM + c16*8);
    *(uint4*)(whh_lds + lr*1024 + ((c16*16) ^ ((lr&7)<<4))) = v;
  }
  for (int c = tid; c < 96*12; c += 512){
    int lr = c / 12, c16 = c % 12;
    int g = lr >> 5, jl = lr & 31;
    int gr = g*512 + j0 + jl;
    uint4 v = *(const uint4*)(wih_g + (size_t)gr*KIN_P + c16*8);
    *(uint4*)(wih_lds + lr*192 + ((c16*16) ^ ((lr&3)<<4))) = v;
  }
  __syncthreads();

  int jl_mine = h16*16 + lj;
  int jg = j0 + jl_mine;
  const float* bih = dir ? bih_b : bih_f;
  const float* bhh = dir ? bhh_b : bhh_f;
  float brz = bih[jg] + bhh[jg];
  float bzz = bih[512+jg] + bhh[512+jg];
  float bxn = bih[1024+jg];
  float bhn = bhh[1024+jg];
  float hreg[4] = {0.f,0.f,0.f,0.f};
  unsigned int* hb = hbuf + (size_t)dir*3*64*256;

  // prefetch xT A-operands for the first step (off critical path thereafter)
  short8 a_pre[3];
  {
    int t0 = dir ? (T_LEN-1) : 0;
    const unsigned short* ar = xT + (size_t)(t0*64 + m0 + lj)*KIN_P + lg*8;
    a_pre[0] = *(const short8*)(ar);
    a_pre[1] = *(const short8*)(ar + 32);
    a_pre[2] = *(const short8*)(ar + 64);
  }

  for (int ts = 0; ts < T_LEN; ts++){
    int t = dir ? (T_LEN-1-ts) : ts;
    int s_r = ts % 3, s_w = (ts+1) % 3, s_s = (ts+2) % 3;
    f32x4 aR={0.f,0.f,0.f,0.f}, aZ={0.f,0.f,0.f,0.f}, aXN={0.f,0.f,0.f,0.f}, aHN={0.f,0.f,0.f,0.f};

    // input-projection from prefetched registers (runs at MFMA issue rate)
    #pragma unroll
    for (int kt=0; kt<3; kt++){
      int lr0 = jl_mine, lr1 = 32 + jl_mine, lr2 = 64 + jl_mine;
      int co = kt*64 + lg*16;
      short8 b0 = *(const short8*)(wih_lds + lr0*192 + (co ^ ((lr0&3)<<4)));
      short8 b1 = *(const short8*)(wih_lds + lr1*192 + (co ^ ((lr1&3)<<4)));
      short8 b2 = *(const short8*)(wih_lds + lr2*192 + (co ^ ((lr2&3)<<4)));
      aR  = MFMA(a_pre[kt], b0, aR);
      aZ  = MFMA(a_pre[kt], b1, aZ);
      aXN = MFMA(a_pre[kt], b2, aXN);
    }
    // issue next-step xT prefetch (latency hides under poll + recurrent + publish)
    {
      int tn = dir ? (t > 0 ? t-1 : 0) : (t < T_LEN-1 ? t+1 : t);
      const unsigned short* ar = xT + (size_t)(tn*64 + m0 + lj)*KIN_P + lg*8;
      a_pre[0] = *(const short8*)(ar);
      a_pre[1] = *(const short8*)(ar + 32);
      a_pre[2] = *(const short8*)(ar + 64);
    }

    // incremental poll-and-consume of h(ts): per 32-col chunk, MFMA on arrival
    {
      const unsigned long long* h64 = (const unsigned long long*)(hb + s_r*64*256)
          + ((((m0+lj)*256) + lg*4) >> 1);
      unsigned int done = 0;
      for (int rounds = 0; done != 0xFFFFu && rounds < POLL_MAX; ++rounds){
        unsigned long long hv0[16], hv1[16];
        #pragma unroll
        for (int kt=0; kt<16; kt++) if (!(done & (1u<<kt))){
          hv0[kt] = __hip_atomic_load(h64 + kt*8 + 0, __ATOMIC_RELAXED, AGENT);
          hv1[kt] = __hip_atomic_load(h64 + kt*8 + 1, __ATOMIC_RELAXED, AGENT);
        }
        #pragma unroll
        for (int kt=0; kt<16; kt++) if (!(done & (1u<<kt))){
          unsigned int a = (unsigned int)hv0[kt], b = (unsigned int)(hv0[kt]>>32);
          unsigned int c = (unsigned int)hv1[kt], d = (unsigned int)(hv1[kt]>>32);
          bool fresh = (a!=SENT) && (b!=SENT) && (c!=SENT) && (d!=SENT);
          if (__all((int)fresh)){
            union { unsigned long long u[2]; short8 s; } cv;
            cv.u[0] = hv0[kt]; cv.u[1] = hv1[kt];
            int lr0 = jl_mine, lr1 = 32 + jl_mine, lr2 = 64 + jl_mine;
            int co = kt*64 + lg*16;
            short8 b0 = *(const short8*)(whh_lds + lr0*1024 + (co ^ ((lr0&7)<<4)));
            short8 b1 = *(const short8*)(whh_lds + lr1*1024 + (co ^ ((lr1&7)<<4)));
            short8 b2 = *(const short8*)(whh_lds + lr2*1024 + (co ^ ((lr2&7)<<4)));
            aR  = MFMA(cv.s, b0, aR);
            aZ  = MFMA(cv.s, b1, aZ);
            aHN = MFMA(cv.s, b2, aHN);
            done |= 1u<<kt;
          }
        }
        if (done != 0xFFFFu) __builtin_amdgcn_s_sleep(1);   // decongest fabric
      }
    }

    float hnew[4];
    #pragma unroll
    for (int i=0;i<4;i++){
      float r = sigm(aR[i] + brz);
      float z = sigm(aZ[i] + bzz);
      float nn = tanh_f(aXN[i] + bxn + r*(aHN[i] + bhn));
      hnew[i] = (1.0f - z)*nn + z*hreg[i];
      hreg[i] = hnew[i];
    }

    if (ts < T_LEN-1){
      unsigned int packed[4];
      #pragma unroll
      for (int i=0;i<4;i++){
        unsigned short mybf = f2bf(hnew[i]);
        unsigned short ot = (unsigned short)__shfl_xor((int)mybf, 1, 64);
        packed[i] = (unsigned int)mybf | ((unsigned int)ot << 16);
      }
      if ((l & 1) == 0){
        unsigned int* hs = hb + s_s*64*256;
        unsigned int* hw = hb + s_w*64*256;
        #pragma unroll
        for (int i=0;i<4;i++){
          int b = m0 + lg*4 + i;
          __hip_atomic_store(hs + b*256 + (jg>>1), SENT, __ATOMIC_RELAXED, AGENT);
          __hip_atomic_store(hw + b*256 + (jg>>1), packed[i], __ATOMIC_RELAXED, AGENT);
        }
      }
    }

    #pragma unroll
    for (int i=0;i<4;i++){
      int b = m0 + lg*4 + i;
      l0out[(size_t)(t*64+b)*1024 + dir*512 + jg] = f2bf(hnew[i]);
    }
  }
}

// ---------------- layer 1: fused input-proj + fwd recurrence; bwd is ONE step ----------------
__launch_bounds__(256)
__global__ void k_gru1(const unsigned short* __restrict__ l0out,
                       const unsigned short* __restrict__ wih1,
                       const unsigned short* __restrict__ whh1f,
                       const float* __restrict__ bih_f, const float* __restrict__ bhh_f,
                       const float* __restrict__ bih_b, const float* __restrict__ bhh_b,
                       float* __restrict__ l1cat,
                       unsigned int* __restrict__ hbuf)   // [3][64][256] dwords
{
  int bid = blockIdx.x;
  int bwd = bid >= 32;
  int n = bwd ? bid - 32 : bid;
  int j0 = n*16;
  int tid = threadIdx.x;
  int w = tid>>6, l = tid&63;
  int m0 = w*16, lj = l&15, lg = l>>4;

  __shared__ unsigned char lds[48*2048 + 48*1024];
  unsigned char* wih_lds = lds;
  unsigned char* whh_lds = lds + 48*2048;
  const unsigned short* wih_g = wih1 + (bwd ? (size_t)G3*1024 : 0);

  for (int c = tid; c < 48*128; c += 256){
    int lr = c >> 7, c16 = c & 127;
    int g = lr >> 4, jl = lr & 15;
    int gr = g*512 + j0 + jl;
    uint4 v = *(const uint4*)(wih_g + (size_t)gr*1024 + c16*8);
    *(uint4*)(wih_lds + lr*2048 + ((c16*16) ^ ((lr&7)<<4))) = v;
  }
  if (!bwd){
    for (int c = tid; c < 48*64; c += 256){
      int lr = c >> 6, c16 = c & 63;
      int g = lr >> 4, jl = lr & 15;
      int gr = g*512 + j0 + jl;
      uint4 v = *(const uint4*)(whh1f + (size_t)gr*HDIM + c16*8);
      *(uint4*)(whh_lds + lr*1024 + ((c16*16) ^ ((lr&7)<<4))) = v;
    }
  }
  __syncthreads();

  int jg = j0 + lj;
  const float* bih = bwd ? bih_b : bih_f;
  const float* bhh = bwd ? bhh_b : bhh_f;
  float brz = bih[jg] + bhh[jg];
  float bzz = bih[512+jg] + bhh[512+jg];
  float bxn = bih[1024+jg];
  float bhn = bhh[1024+jg];

  if (bwd){
    int t = T_LEN-1;
    f32x4 aR={0.f,0.f,0.f,0.f}, aZ={0.f,0.f,0.f,0.f}, aXN={0.f,0.f,0.f,0.f};
    const unsigned short* arow = l0out + (size_t)(t*64 + m0 + lj)*1024 + lg*8;
    #pragma unroll 8
    for (int kt=0; kt<32; kt++){
      short8 a = *(const short8*)(arow + kt*32);
      int lr0 = lj, lr1 = 16+lj, lr2 = 32+lj;
      int co = kt*64 + lg*16;
      short8 b0 = *(const short8*)(wih_lds + lr0*2048 + (co ^ ((lr0&7)<<4)));
      short8 b1 = *(const short8*)(wih_lds + lr1*2048 + (co ^ ((lr1&7)<<4)));
      short8 b2 = *(const short8*)(wih_lds + lr2*2048 + (co ^ ((lr2&7)<<4)));
      aR = MFMA(a,b0,aR); aZ = MFMA(a,b1,aZ); aXN = MFMA(a,b2,aXN);
    }
    #pragma unroll
    for (int i=0;i<4;i++){
      float r = sigm(aR[i] + brz);
      float z = sigm(aZ[i] + bzz);
      float nn = tanh_f(aXN[i] + bxn + r*bhn);
      l1cat[(size_t)(m0 + lg*4 + i)*1024 + 512 + jg] = (1.0f - z)*nn;
    }
    return;
  }

  float hreg[4] = {0.f,0.f,0.f,0.f};

  // prefetch first half of l0out A-operands for ts=0
  short8 ap[16];
  {
    const unsigned short* ar = l0out + (size_t)(0*64 + m0 + lj)*1024 + lg*8;
    #pragma unroll
    for (int k=0;k<16;k++) ap[k] = *(const short8*)(ar + k*32);
  }

  for (int ts = 0; ts < T_LEN; ts++){
    int s_r = ts % 3, s_w = (ts+1) % 3, s_s = (ts+2) % 3;
    f32x4 aR={0.f,0.f,0.f,0.f}, aZ={0.f,0.f,0.f,0.f}, aXN={0.f,0.f,0.f,0.f}, aHN={0.f,0.f,0.f,0.f};
    const unsigned short* arow = l0out + (size_t)(ts*64 + m0 + lj)*1024 + lg*8;

    // issue second-half A loads, then MFMA first half (hides the loads), then second half
    short8 bp[16];
    #pragma unroll
    for (int k=0;k<16;k++) bp[k] = *(const short8*)(arow + (16+k)*32);
    #pragma unroll
    for (int k=0;k<16;k++){
      int lr0 = lj, lr1 = 16+lj, lr2 = 32+lj;
      int co = k*64 + lg*16;
      short8 b0 = *(const short8*)(wih_lds + lr0*2048 + (co ^ ((lr0&7)<<4)));
      short8 b1 = *(const short8*)(wih_lds + lr1*2048 + (co ^ ((lr1&7)<<4)));
      short8 b2 = *(const short8*)(wih_lds + lr2*2048 + (co ^ ((lr2&7)<<4)));
      aR = MFMA(ap[k],b0,aR); aZ = MFMA(ap[k],b1,aZ); aXN = MFMA(ap[k],b2,aXN);
    }
    #pragma unroll
    for (int k=0;k<16;k++){
      int kt = 16+k;
      int lr0 = lj, lr1 = 16+lj, lr2 = 32+lj;
      int co = kt*64 + lg*16;
      short8 b0 = *(const short8*)(wih_lds + lr0*2048 + (co ^ ((lr0&7)<<4)));
      short8 b1 = *(const short8*)(wih_lds + lr1*2048 + (co ^ ((lr1&7)<<4)));
      short8 b2 = *(const short8*)(wih_lds + lr2*2048 + (co ^ ((lr2&7)<<4)));
      aR = MFMA(bp[k],b0,aR); aZ = MFMA(bp[k],b1,aZ); aXN = MFMA(bp[k],b2,aXN);
    }
    // prefetch next step's first half (hides under poll + recurrent + publish)
    if (ts + 1 < T_LEN){
      const unsigned short* ar2 = l0out + (size_t)((ts+1)*64 + m0 + lj)*1024 + lg*8;
      #pragma unroll
      for (int k=0;k<16;k++) ap[k] = *(const short8*)(ar2 + k*32);
    }

    // incremental poll-and-consume of h(ts)
    {
      const unsigned long long* h64 = (const unsigned long long*)(hbuf + s_r*64*256)
          + ((((m0+lj)*256) + lg*4) >> 1);
      unsigned int done = 0;
      for (int rounds = 0; done != 0xFFFFu && rounds < POLL_MAX; ++rounds){
        unsigned long long hv0[16], hv1[16];
        #pragma unroll
        for (int kt=0; kt<16; kt++) if (!(done & (1u<<kt))){
          hv0[kt] = __hip_atomic_load(h64 + kt*8 + 0, __ATOMIC_RELAXED, AGENT);
          hv1[kt] = __hip_atomic_load(h64 + kt*8 + 1, __ATOMIC_RELAXED, AGENT);
        }
        #pragma unroll
        for (int kt=0; kt<16; kt++) if (!(done & (1u<<kt))){
          unsigned int a = (unsigned int)hv0[kt], b = (unsigned int)(hv0[kt]>>32);
          unsigned int c = (unsigned int)hv1[kt], d = (unsigned int)(hv1[kt]>>32);
          bool fresh = (a!=SENT) && (b!=SENT) && (c!=SENT) && (d!=SENT);
          if (__all((int)fresh)){
            union { unsigned long long u[2]; short8 s; } cv;
            cv.u[0] = hv0[kt]; cv.u[1] = hv1[kt];
            int lr0 = lj, lr1 = 16+lj, lr2 = 32+lj;
            int co = kt*64 + lg*16;
            short8 b0 = *(const short8*)(whh_lds + lr0*1024 + (co ^ ((lr0&7)<<4)));
            short8 b1 = *(const short8*)(whh_lds + lr1*1024 + (co ^ ((lr1&7)<<4)));
            short8 b2 = *(const short8*)(whh_lds + lr2*1024 + (co ^ ((lr2&7)<<4)));
            aR = MFMA(cv.s,b0,aR); aZ = MFMA(cv.s,b1,aZ); aHN = MFMA(cv.s,b2,aHN);
            done |= 1u<<kt;
          }
        }
        if (done != 0xFFFFu) __builtin_amdgcn_s_sleep(1);
      }
    }

    float hnew[4];
    #pragma unroll
    for (int i=0;i<4;i++){
      float r = sigm(aR[i] + brz);
      float z = sigm(aZ[i] + bzz);
      float nn = tanh_f(aXN[i] + bxn + r*(aHN[i] + bhn));
      hnew[i] = (1.0f - z)*nn + z*hreg[i];
      hreg[i] = hnew[i];
    }
    if (ts < T_LEN-1){
      unsigned int packed[4];
      #pragma unroll
      for (int i=0;i<4;i++){
        unsigned short mybf = f2bf(hnew[i]);
        unsigned short ot = (unsigned short)__shfl_xor((int)mybf, 1, 64);
        packed[i] = (unsigned int)mybf | ((unsigned int)ot << 16);
      }
      if ((l & 1) == 0){
        unsigned int* hs = hbuf + s_s*64*256;
        unsigned int* hw = hbuf + s_w*64*256;
        #pragma unroll
        for (int i=0;i<4;i++){
          int b = m0 + lg*4 + i;
          __hip_atomic_store(hs + b*256 + (jg>>1), SENT, __ATOMIC_RELAXED, AGENT);
          __hip_atomic_store(hw + b*256 + (jg>>1), packed[i], __ATOMIC_RELAXED, AGENT);
        }
      }
    } else {
      #pragma unroll
      for (int i=0;i<4;i++)
        l1cat[(size_t)(m0 + lg*4 + i)*1024 + jg] = hnew[i];
    }
  }
}

// ---------------- final FC ----------------
__global__ void k_fc(const float* __restrict__ l1cat, const float* __restrict__ fcw,
                     const float* __restrict__ fcb, float* __restrict__ out){
  int idx = blockIdx.x*256 + threadIdx.x;
  if (idx >= 64*12) return;
  int b = idx / 12, o = idx % 12;
  float s = fcb[o];
  for (int k=0;k<1024;k++) s += l1cat[b*1024+k]*fcw[o*1024+k];
  out[idx] = s;
}

extern "C" void kernel_launch(void* const* d_in, const int* in_sizes, int n_in,
                              void* d_out, int out_size, void* d_ws, size_t ws_size,
                              hipStream_t stream){
  const float* x     = (const float*)d_in[0];
  const float* wih0f = (const float*)d_in[1];
  const float* whh0f = (const float*)d_in[2];
  const float* bih0f = (const float*)d_in[3];
  const float* bhh0f = (const float*)d_in[4];
  const float* wih0b = (const float*)d_in[5];
  const float* whh0b = (const float*)d_in[6];
  const float* bih0b = (const float*)d_in[7];
  const float* bhh0b = (const float*)d_in[8];
  const float* wih1f = (const float*)d_in[9];
  const float* whh1f = (const float*)d_in[10];
  const float* bih1f = (const float*)d_in[11];
  const float* bhh1f = (const float*)d_in[12];
  const float* wih1b = (const float*)d_in[13];
  const float* bih1b = (const float*)d_in[15];
  const float* bhh1b = (const float*)d_in[16];
  const float* fcw   = (const float*)d_in[17];
  const float* fcb   = (const float*)d_in[18];

  const size_t SLOT = (size_t)64*256*4;   // 64 KB per ring slot

  char* ws = (char*)d_ws;
  size_t off = 0;
  auto alloc = [&](size_t bytes)->void*{ void* p = ws + off; off = (off + bytes + 255) & ~(size_t)255; return p; };
  unsigned short* xT    = (unsigned short*)alloc((size_t)64000*96*2);
  unsigned short* whh0c = (unsigned short*)alloc((size_t)2*1536*512*2);
  unsigned short* wih0c = (unsigned short*)alloc((size_t)2*1536*96*2);
  unsigned short* wih1c = (unsigned short*)alloc((size_t)2*1536*1024*2);
  unsigned short* whh1c = (unsigned short*)alloc((size_t)1536*512*2);
  unsigned short* l0out = (unsigned short*)alloc((size_t)64000*1024*2);
  unsigned int*   hbB   = (unsigned int*)alloc((size_t)2*3*SLOT);   // [2][3][64][256]
  unsigned int*   hbD   = (unsigned int*)alloc((size_t)3*SLOT);     // [3][64][256]
  float*          l1cat = (float*)alloc((size_t)64*1024*4);

  if (off > ws_size){
    k_sentinel<<<(out_size+255)/256,256,0,stream>>>((float*)d_out, out_size);
    return;
  }

  // ring init: slot 0 = zeros (h0 = 0), slots 1..2 = 0xFF sentinel bytes
  for (int d = 0; d < 2; d++){
    char* base = (char*)hbB + (size_t)d*3*SLOT;
    hipMemsetAsync(base, 0, SLOT, stream);
    hipMemsetAsync(base + SLOT, 0xFF, 2*SLOT, stream);
  }
  hipMemsetAsync(hbD, 0, SLOT, stream);
  hipMemsetAsync((char*)hbD + SLOT, 0xFF, 2*SLOT, stream);

  k_conv<<<3072,256,0,stream>>>(whh0f, whh0c, 786432);
  k_conv<<<3072,256,0,stream>>>(whh0b, whh0c+786432, 786432);
  k_conv_pad<<<576,256,0,stream>>>(wih0f, wih0c, 1536, 69, 96);
  k_conv_pad<<<576,256,0,stream>>>(wih0b, wih0c+1536*96, 1536, 69, 96);
  k_conv<<<6144,256,0,stream>>>(wih1f, wih1c, 1572864);
  k_conv<<<6144,256,0,stream>>>(wih1b, wih1c+1572864, 1572864);
  k_conv<<<3072,256,0,stream>>>(whh1f, whh1c, 786432);
  k_xpose<<<1024,64,0,stream>>>(x, xT);

  k_gru0<<<32,512,0,stream>>>(xT, whh0c, wih0c, bih0f,bhh0f,bih0b,bhh0b, l0out, hbB);
  k_gru1<<<64,256,0,stream>>>(l0out, wih1c, whh1c, bih1f,bhh1f,bih1b,bhh1b, l1cat, hbD);
  k_fc<<<3,256,0,stream>>>(l1cat, fcw, fcb, (float*)d_out);
}

// Round 11
// 18914.915 us; speedup vs baseline: 1.1171x; 1.1171x over previous
//
#include <hip/hip_runtime.h>
#include <hip/hip_bf16.h>
#include <stdint.h>

#define T_LEN 1000
#define KIN   69
#define KIN_P 96
#define G3    1536
#define HDIM  512
#define POLL_MAX 30000
#define SENT 0xFFFFFFFFu   // bf16 NaN|NaN — unreachable for GRU h in (-1,1)

typedef __attribute__((ext_vector_type(8))) short short8;
typedef __attribute__((ext_vector_type(4))) float f32x4;

#define MFMA(a,b,c) __builtin_amdgcn_mfma_f32_16x16x32_bf16((a),(b),(c),0,0,0)
#define AGENT __HIP_MEMORY_SCOPE_AGENT

static __device__ __forceinline__ float sigm(float x){ return 1.0f/(1.0f+__expf(-x)); }
static __device__ __forceinline__ float tanh_f(float x){
  float a = fabsf(x);
  float e = __expf(2.0f*a);
  float t = 1.0f - 2.0f/(e+1.0f);
  return x >= 0.0f ? t : -t;
}
static __device__ __forceinline__ unsigned short f2bf(float f){
  union { float f; unsigned int u; } v; v.f = f;
  unsigned int u = v.u;
  return (unsigned short)((u + 0x7fffu + ((u>>16)&1u)) >> 16);   // RNE
}

// Poll 16 chunks (16B each) of this thread's h row portion straight from the LLC.
// Freshness = no dword equals SENT. The poll IS the data load (zero extra RTs).
static __device__ __forceinline__ void poll_h(const unsigned long long* h64,
                                              unsigned long long hv[32]){
  unsigned int ok = 0;
  for (int rounds = 0; ok != 0xFFFFu && rounds < POLL_MAX; ++rounds){
    #pragma unroll
    for (int kt=0; kt<16; kt++) if (!(ok & (1u<<kt))){
      hv[2*kt]   = __hip_atomic_load(h64 + kt*8 + 0, __ATOMIC_RELAXED, AGENT);
      hv[2*kt+1] = __hip_atomic_load(h64 + kt*8 + 1, __ATOMIC_RELAXED, AGENT);
    }
    #pragma unroll
    for (int kt=0; kt<16; kt++) if (!(ok & (1u<<kt))){
      unsigned int a = (unsigned int)hv[2*kt],   b = (unsigned int)(hv[2*kt]>>32);
      unsigned int c = (unsigned int)hv[2*kt+1], d = (unsigned int)(hv[2*kt+1]>>32);
      if (a!=SENT && b!=SENT && c!=SENT && d!=SENT) ok |= 1u<<kt;
    }
  }
}

// Clock-keeper v2: dependent-FMA busy loop holds SMU activity (SCLK) high on idle
// CUs. ONLY thread 0 polls the done counter (1 load per ~0.9 µs per block — no
// fabric hotspot, unlike R10's all-thread poll); exit broadcast via volatile LDS.
// Hard cap ~20 ms = hang-proof.
static __device__ __forceinline__ void keeper(const unsigned int* done, unsigned int target){
  volatile __shared__ unsigned int quit;
  if (threadIdx.x == 0) quit = 0u;
  __syncthreads();
  float a = 0.5f + 1e-6f*(float)(threadIdx.x & 63);
  for (int it = 0; it < 24000; ++it){
    #pragma unroll 4
    for (int k=0;k<512;k++) a = __builtin_fmaf(a, 1.0000001f, 1e-9f);
    asm volatile("" :: "v"(a));               // keep live (rule #17)
    if (threadIdx.x == 0 &&
        __hip_atomic_load(done, __ATOMIC_RELAXED, AGENT) >= target) quit = 1u;
    if (quit) break;
  }
}

// ---------------- small converters ----------------
__global__ void k_conv(const float* __restrict__ src, unsigned short* __restrict__ dst, int n){
  int i = blockIdx.x*256 + threadIdx.x;
  if (i < n) dst[i] = f2bf(src[i]);
}
__global__ void k_conv_pad(const float* __restrict__ src, unsigned short* __restrict__ dst,
                           int rows, int ks, int kd){
  int i = blockIdx.x*256 + threadIdx.x;
  int r = i / kd, c = i % kd;
  if (r < rows) dst[i] = (c < ks) ? f2bf(src[r*ks + c]) : (unsigned short)0;
}
__global__ void k_sentinel(float* __restrict__ out, int n){
  int i = blockIdx.x*256 + threadIdx.x;
  if (i < n) out[i] = 1234.5f;
}

// x: [64][69][1000] f32  ->  xT: [(t*64+b)][96] bf16
__global__ void k_xpose(const float* __restrict__ x, unsigned short* __restrict__ xT){
  int b = blockIdx.x & 63, tt = blockIdx.x >> 6;
  int t = tt*64 + threadIdx.x;
  if (t >= T_LEN) return;
  unsigned int* dst = (unsigned int*)(xT + (size_t)(t*64+b)*KIN_P);
  #pragma unroll
  for (int i=0;i<48;i++){
    int k0 = 2*i, k1 = 2*i+1;
    unsigned int lo = (k0<KIN) ? f2bf(x[((size_t)b*KIN + k0)*T_LEN + t]) : 0u;
    unsigned int hi = (k1<KIN) ? f2bf(x[((size_t)b*KIN + k1)*T_LEN + t]) : 0u;
    dst[i] = lo | (hi<<16);
  }
}

// ---------------- layer 0: fused input-proj + bidirectional recurrence ----------------
// blocks 0..31: scan (dir = bid/16, slice = bid%16); blocks 32..255: clock-keepers.
#define NB_B 16
__launch_bounds__(512)
__global__ void k_gru0(const unsigned short* __restrict__ xT,
                       const unsigned short* __restrict__ whh0,
                       const unsigned short* __restrict__ wih0,
                       const float* __restrict__ bih_f, const float* __restrict__ bhh_f,
                       const float* __restrict__ bih_b, const float* __restrict__ bhh_b,
                       unsigned short* __restrict__ l0out,
                       unsigned int* __restrict__ hbuf,   // [2][3][64][256] dwords
                       unsigned int* __restrict__ done)
{
  int bid = blockIdx.x;
  if (bid >= 32){ keeper(done, 32u); return; }
  int dir = bid / NB_B;
  int n   = bid % NB_B;
  int j0  = n*32;
  int tid = threadIdx.x;
  int w = tid>>6, l = tid&63;
  int m0  = (w & 3) * 16;
  int h16 = w >> 2;
  int lj = l & 15, lg = l >> 4;

  __shared__ unsigned char lds[96*1024 + 96*192];
  unsigned char* whh_lds = lds;
  unsigned char* wih_lds = lds + 96*1024;
  const unsigned short* whh_g = whh0 + (size_t)dir*G3*HDIM;
  const unsigned short* wih_g = wih0 + (size_t)dir*G3*KIN_P;

  for (int c = tid; c < 96*64; c += 512){
    int lr = c >> 6, c16 = c & 63;
    int g = lr >> 5, jl = lr & 31;
    int gr = g*512 + j0 + jl;
    uint4 v = *(const uint4*)(whh_g + (size_t)gr*HDIM + c16*8);
    *(uint4*)(whh_lds + lr*1024 + ((c16*16) ^ ((lr&7)<<4))) = v;
  }
  for (int c = tid; c < 96*12; c += 512){
    int lr = c / 12, c16 = c % 12;
    int g = lr >> 5, jl = lr & 31;
    int gr = g*512 + j0 + jl;
    uint4 v = *(const uint4*)(wih_g + (size_t)gr*KIN_P + c16*8);
    *(uint4*)(wih_lds + lr*192 + ((c16*16) ^ ((lr&3)<<4))) = v;
  }
  __syncthreads();

  int jl_mine = h16*16 + lj;
  int jg = j0 + jl_mine;
  const float* bih = dir ? bih_b : bih_f;
  const float* bhh = dir ? bhh_b : bhh_f;
  float brz = bih[jg] + bhh[jg];
  float bzz = bih[512+jg] + bhh[512+jg];
  float bxn = bih[1024+jg];
  float bhn = bhh[1024+jg];
  float hreg[4] = {0.f,0.f,0.f,0.f};
  unsigned int* hb = hbuf + (size_t)dir*3*64*256;

  for (int ts = 0; ts < T_LEN; ts++){
    int t = dir ? (T_LEN-1-ts) : ts;
    int s_r = ts % 3, s_w = (ts+1) % 3, s_s = (ts+2) % 3;
    f32x4 aR={0.f,0.f,0.f,0.f}, aZ={0.f,0.f,0.f,0.f}, aXN={0.f,0.f,0.f,0.f}, aHN={0.f,0.f,0.f,0.f};

    // input-projection (independent of h)
    const unsigned short* arow = xT + (size_t)(t*64 + m0 + lj)*KIN_P + lg*8;
    #pragma unroll
    for (int kt=0; kt<3; kt++){
      short8 a = *(const short8*)(arow + kt*32);
      int lr0 = jl_mine, lr1 = 32 + jl_mine, lr2 = 64 + jl_mine;
      int co = kt*64 + lg*16;
      short8 b0 = *(const short8*)(wih_lds + lr0*192 + (co ^ ((lr0&3)<<4)));
      short8 b1 = *(const short8*)(wih_lds + lr1*192 + (co ^ ((lr1&3)<<4)));
      short8 b2 = *(const short8*)(wih_lds + lr2*192 + (co ^ ((lr2&3)<<4)));
      aR  = MFMA(a, b0, aR);
      aZ  = MFMA(a, b1, aZ);
      aXN = MFMA(a, b2, aXN);
    }

    // poll h(ts) directly (self-announcing data; ts=0 slot holds zeros = fresh)
    unsigned long long hv[32];
    const unsigned long long* h64 = (const unsigned long long*)(hb + s_r*64*256)
        + ((((m0+lj)*256) + lg*4) >> 1);
    poll_h(h64, hv);

    #pragma unroll
    for (int kt=0; kt<16; kt++){
      union { unsigned long long u[2]; short8 s; } cv;
      cv.u[0] = hv[2*kt]; cv.u[1] = hv[2*kt+1];
      int lr0 = jl_mine, lr1 = 32 + jl_mine, lr2 = 64 + jl_mine;
      int co = kt*64 + lg*16;
      short8 b0 = *(const short8*)(whh_lds + lr0*1024 + (co ^ ((lr0&7)<<4)));
      short8 b1 = *(const short8*)(whh_lds + lr1*1024 + (co ^ ((lr1&7)<<4)));
      short8 b2 = *(const short8*)(whh_lds + lr2*1024 + (co ^ ((lr2&7)<<4)));
      aR  = MFMA(cv.s, b0, aR);
      aZ  = MFMA(cv.s, b1, aZ);
      aHN = MFMA(cv.s, b2, aHN);
    }

    float hnew[4];
    #pragma unroll
    for (int i=0;i<4;i++){
      float r = sigm(aR[i] + brz);
      float z = sigm(aZ[i] + bzz);
      float nn = tanh_f(aXN[i] + bxn + r*(aHN[i] + bhn));
      hnew[i] = (1.0f - z)*nn + z*hreg[i];
      hreg[i] = hnew[i];
    }

    if (ts < T_LEN-1){
      unsigned int packed[4];
      #pragma unroll
      for (int i=0;i<4;i++){
        unsigned short mybf = f2bf(hnew[i]);
        unsigned short ot = (unsigned short)__shfl_xor((int)mybf, 1, 64);
        packed[i] = (unsigned int)mybf | ((unsigned int)ot << 16);
      }
      if ((l & 1) == 0){
        unsigned int* hs = hb + s_s*64*256;
        unsigned int* hw = hb + s_w*64*256;
        #pragma unroll
        for (int i=0;i<4;i++){
          int b = m0 + lg*4 + i;
          __hip_atomic_store(hs + b*256 + (jg>>1), SENT, __ATOMIC_RELAXED, AGENT);
          __hip_atomic_store(hw + b*256 + (jg>>1), packed[i], __ATOMIC_RELAXED, AGENT);
        }
      }
    }

    #pragma unroll
    for (int i=0;i<4;i++){
      int b = m0 + lg*4 + i;
      l0out[(size_t)(t*64+b)*1024 + dir*512 + jg] = f2bf(hnew[i]);
    }
  }
  if (tid == 0) __hip_atomic_fetch_add(done, 1u, __ATOMIC_RELAXED, AGENT);
}

// ---------------- layer 1 ----------------
// blocks 0..31: fwd scan; 32..63: bwd single-step; 64..255: clock-keepers.
__launch_bounds__(256)
__global__ void k_gru1(const unsigned short* __restrict__ l0out,
                       const unsigned short* __restrict__ wih1,
                       const unsigned short* __restrict__ whh1f,
                       const float* __restrict__ bih_f, const float* __restrict__ bhh_f,
                       const float* __restrict__ bih_b, const float* __restrict__ bhh_b,
                       float* __restrict__ l1cat,
                       unsigned int* __restrict__ hbuf,   // [3][64][256] dwords
                       unsigned int* __restrict__ done)
{
  int bid = blockIdx.x;
  if (bid >= 64){ keeper(done, 32u); return; }
  int bwd = bid >= 32;
  int n = bwd ? bid - 32 : bid;
  int j0 = n*16;
  int tid = threadIdx.x;
  int w = tid>>6, l = tid&63;
  int m0 = w*16, lj = l&15, lg = l>>4;

  __shared__ unsigned char lds[48*2048 + 48*1024];
  unsigned char* wih_lds = lds;
  unsigned char* whh_lds = lds + 48*2048;
  const unsigned short* wih_g = wih1 + (bwd ? (size_t)G3*1024 : 0);

  for (int c = tid; c < 48*128; c += 256){
    int lr = c >> 7, c16 = c & 127;
    int g = lr >> 4, jl = lr & 15;
    int gr = g*512 + j0 + jl;
    uint4 v = *(const uint4*)(wih_g + (size_t)gr*1024 + c16*8);
    *(uint4*)(wih_lds + lr*2048 + ((c16*16) ^ ((lr&7)<<4))) = v;
  }
  if (!bwd){
    for (int c = tid; c < 48*64; c += 256){
      int lr = c >> 6, c16 = c & 63;
      int g = lr >> 4, jl = lr & 15;
      int gr = g*512 + j0 + jl;
      uint4 v = *(const uint4*)(whh1f + (size_t)gr*HDIM + c16*8);
      *(uint4*)(whh_lds + lr*1024 + ((c16*16) ^ ((lr&7)<<4))) = v;
    }
  }
  __syncthreads();

  int jg = j0 + lj;
  const float* bih = bwd ? bih_b : bih_f;
  const float* bhh = bwd ? bhh_b : bhh_f;
  float brz = bih[jg] + bhh[jg];
  float bzz = bih[512+jg] + bhh[512+jg];
  float bxn = bih[1024+jg];
  float bhn = bhh[1024+jg];

  if (bwd){
    int t = T_LEN-1;
    f32x4 aR={0.f,0.f,0.f,0.f}, aZ={0.f,0.f,0.f,0.f}, aXN={0.f,0.f,0.f,0.f};
    const unsigned short* arow = l0out + (size_t)(t*64 + m0 + lj)*1024 + lg*8;
    #pragma unroll 8
    for (int kt=0; kt<32; kt++){
      short8 a = *(const short8*)(arow + kt*32);
      int lr0 = lj, lr1 = 16+lj, lr2 = 32+lj;
      int co = kt*64 + lg*16;
      short8 b0 = *(const short8*)(wih_lds + lr0*2048 + (co ^ ((lr0&7)<<4)));
      short8 b1 = *(const short8*)(wih_lds + lr1*2048 + (co ^ ((lr1&7)<<4)));
      short8 b2 = *(const short8*)(wih_lds + lr2*2048 + (co ^ ((lr2&7)<<4)));
      aR = MFMA(a,b0,aR); aZ = MFMA(a,b1,aZ); aXN = MFMA(a,b2,aXN);
    }
    #pragma unroll
    for (int i=0;i<4;i++){
      float r = sigm(aR[i] + brz);
      float z = sigm(aZ[i] + bzz);
      float nn = tanh_f(aXN[i] + bxn + r*bhn);
      l1cat[(size_t)(m0 + lg*4 + i)*1024 + 512 + jg] = (1.0f - z)*nn;
    }
    return;
  }

  float hreg[4] = {0.f,0.f,0.f,0.f};
  for (int ts = 0; ts < T_LEN; ts++){
    int s_r = ts % 3, s_w = (ts+1) % 3, s_s = (ts+2) % 3;
    f32x4 aR={0.f,0.f,0.f,0.f}, aZ={0.f,0.f,0.f,0.f}, aXN={0.f,0.f,0.f,0.f}, aHN={0.f,0.f,0.f,0.f};
    const unsigned short* arow = l0out + (size_t)(ts*64 + m0 + lj)*1024 + lg*8;
    #pragma unroll 8
    for (int kt=0; kt<32; kt++){
      short8 a = *(const short8*)(arow + kt*32);
      int lr0 = lj, lr1 = 16+lj, lr2 = 32+lj;
      int co = kt*64 + lg*16;
      short8 b0 = *(const short8*)(wih_lds + lr0*2048 + (co ^ ((lr0&7)<<4)));
      short8 b1 = *(const short8*)(wih_lds + lr1*2048 + (co ^ ((lr1&7)<<4)));
      short8 b2 = *(const short8*)(wih_lds + lr2*2048 + (co ^ ((lr2&7)<<4)));
      aR = MFMA(a,b0,aR); aZ = MFMA(a,b1,aZ); aXN = MFMA(a,b2,aXN);
    }

    unsigned long long hv[32];
    const unsigned long long* h64 = (const unsigned long long*)(hbuf + s_r*64*256)
        + ((((m0+lj)*256) + lg*4) >> 1);
    poll_h(h64, hv);

    #pragma unroll
    for (int kt=0; kt<16; kt++){
      union { unsigned long long u[2]; short8 s; } cv;
      cv.u[0] = hv[2*kt]; cv.u[1] = hv[2*kt+1];
      int lr0 = lj, lr1 = 16+lj, lr2 = 32+lj;
      int co = kt*64 + lg*16;
      short8 b0 = *(const short8*)(whh_lds + lr0*1024 + (co ^ ((lr0&7)<<4)));
      short8 b1 = *(const short8*)(whh_lds + lr1*1024 + (co ^ ((lr1&7)<<4)));
      short8 b2 = *(const short8*)(whh_lds + lr2*1024 + (co ^ ((lr2&7)<<4)));
      aR = MFMA(cv.s,b0,aR); aZ = MFMA(cv.s,b1,aZ); aHN = MFMA(cv.s,b2,aHN);
    }
    float hnew[4];
    #pragma unroll
    for (int i=0;i<4;i++){
      float r = sigm(aR[i] + brz);
      float z = sigm(aZ[i] + bzz);
      float nn = tanh_f(aXN[i] + bxn + r*(aHN[i] + bhn));
      hnew[i] = (1.0f - z)*nn + z*hreg[i];
      hreg[i] = hnew[i];
    }
    if (ts < T_LEN-1){
      unsigned int packed[4];
      #pragma unroll
      for (int i=0;i<4;i++){
        unsigned short mybf = f2bf(hnew[i]);
        unsigned short ot = (unsigned short)__shfl_xor((int)mybf, 1, 64);
        packed[i] = (unsigned int)mybf | ((unsigned int)ot << 16);
      }
      if ((l & 1) == 0){
        unsigned int* hs = hbuf + s_s*64*256;
        unsigned int* hw = hbuf + s_w*64*256;
        #pragma unroll
        for (int i=0;i<4;i++){
          int b = m0 + lg*4 + i;
          __hip_atomic_store(hs + b*256 + (jg>>1), SENT, __ATOMIC_RELAXED, AGENT);
          __hip_atomic_store(hw + b*256 + (jg>>1), packed[i], __ATOMIC_RELAXED, AGENT);
        }
      }
    } else {
      #pragma unroll
      for (int i=0;i<4;i++)
        l1cat[(size_t)(m0 + lg*4 + i)*1024 + jg] = hnew[i];
    }
  }
  if (tid == 0) __hip_atomic_fetch_add(done, 1u, __ATOMIC_RELAXED, AGENT);
}

// ---------------- final FC ----------------
__global__ void k_fc(const float* __restrict__ l1cat, const float* __restrict__ fcw,
                     const float* __restrict__ fcb, float* __restrict__ out){
  int idx = blockIdx.x*256 + threadIdx.x;
  if (idx >= 64*12) return;
  int b = idx / 12, o = idx % 12;
  float s = fcb[o];
  for (int k=0;k<1024;k++) s += l1cat[b*1024+k]*fcw[o*1024+k];
  out[idx] = s;
}

extern "C" void kernel_launch(void* const* d_in, const int* in_sizes, int n_in,
                              void* d_out, int out_size, void* d_ws, size_t ws_size,
                              hipStream_t stream){
  const float* x     = (const float*)d_in[0];
  const float* wih0f = (const float*)d_in[1];
  const float* whh0f = (const float*)d_in[2];
  const float* bih0f = (const float*)d_in[3];
  const float* bhh0f = (const float*)d_in[4];
  const float* wih0b = (const float*)d_in[5];
  const float* whh0b = (const float*)d_in[6];
  const float* bih0b = (const float*)d_in[7];
  const float* bhh0b = (const float*)d_in[8];
  const float* wih1f = (const float*)d_in[9];
  const float* whh1f = (const float*)d_in[10];
  const float* bih1f = (const float*)d_in[11];
  const float* bhh1f = (const float*)d_in[12];
  const float* wih1b = (const float*)d_in[13];
  const float* bih1b = (const float*)d_in[15];
  const float* bhh1b = (const float*)d_in[16];
  const float* fcw   = (const float*)d_in[17];
  const float* fcb   = (const float*)d_in[18];

  const size_t SLOT = (size_t)64*256*4;   // 64 KB per ring slot

  char* ws = (char*)d_ws;
  size_t off = 0;
  auto alloc = [&](size_t bytes)->void*{ void* p = ws + off; off = (off + bytes + 255) & ~(size_t)255; return p; };
  unsigned short* xT    = (unsigned short*)alloc((size_t)64000*96*2);
  unsigned short* whh0c = (unsigned short*)alloc((size_t)2*1536*512*2);
  unsigned short* wih0c = (unsigned short*)alloc((size_t)2*1536*96*2);
  unsigned short* wih1c = (unsigned short*)alloc((size_t)2*1536*1024*2);
  unsigned short* whh1c = (unsigned short*)alloc((size_t)1536*512*2);
  unsigned short* l0out = (unsigned short*)alloc((size_t)64000*1024*2);
  unsigned int*   hbB   = (unsigned int*)alloc((size_t)2*3*SLOT);   // [2][3][64][256]
  unsigned int*   hbD   = (unsigned int*)alloc((size_t)3*SLOT);     // [3][64][256]
  float*          l1cat = (float*)alloc((size_t)64*1024*4);
  unsigned int*   sync  = (unsigned int*)alloc(256);                // done0 | done1

  if (off > ws_size){
    k_sentinel<<<(out_size+255)/256,256,0,stream>>>((float*)d_out, out_size);
    return;
  }

  // ring init: slot 0 = zeros (h0 = 0), slots 1..2 = 0xFF sentinel bytes
  for (int d = 0; d < 2; d++){
    char* base = (char*)hbB + (size_t)d*3*SLOT;
    hipMemsetAsync(base, 0, SLOT, stream);
    hipMemsetAsync(base + SLOT, 0xFF, 2*SLOT, stream);
  }
  hipMemsetAsync(hbD, 0, SLOT, stream);
  hipMemsetAsync((char*)hbD + SLOT, 0xFF, 2*SLOT, stream);
  hipMemsetAsync(sync, 0, 256, stream);

  k_conv<<<3072,256,0,stream>>>(whh0f, whh0c, 786432);
  k_conv<<<3072,256,0,stream>>>(whh0b, whh0c+786432, 786432);
  k_conv_pad<<<576,256,0,stream>>>(wih0f, wih0c, 1536, 69, 96);
  k_conv_pad<<<576,256,0,stream>>>(wih0b, wih0c+1536*96, 1536, 69, 96);
  k_conv<<<6144,256,0,stream>>>(wih1f, wih1c, 1572864);
  k_conv<<<6144,256,0,stream>>>(wih1b, wih1c+1572864, 1572864);
  k_conv<<<3072,256,0,stream>>>(whh1f, whh1c, 786432);
  k_xpose<<<1024,64,0,stream>>>(x, xT);

  k_gru0<<<256,512,0,stream>>>(xT, whh0c, wih0c, bih0f,bhh0f,bih0b,bhh0b, l0out, hbB, sync);
  k_gru1<<<256,256,0,stream>>>(l0out, wih1c, whh1c, bih1f,bhh1f,bih1b,bhh1b, l1cat, hbD, sync+32);
  k_fc<<<3,256,0,stream>>>(l1cat, fcw, fcb, (float*)d_out);
}

// Round 12
// 18904.205 us; speedup vs baseline: 1.1177x; 1.0006x over previous
//
#include <hip/hip_runtime.h>
#include <hip/hip_bf16.h>
#include <stdint.h>

#define T_LEN 1000
#define KIN   69
#define KIN_P 96
#define G3    1536
#define HDIM  512
#define POLL_MAX 30000
#define SENT 0xFFFFFFFFu   // bf16 NaN|NaN — unreachable for GRU h in (-1,1)

typedef __attribute__((ext_vector_type(8))) short short8;
typedef __attribute__((ext_vector_type(4))) float f32x4;

#define MFMA(a,b,c) __builtin_amdgcn_mfma_f32_16x16x32_bf16((a),(b),(c),0,0,0)
#define AGENT __HIP_MEMORY_SCOPE_AGENT

static __device__ __forceinline__ float sigm(float x){ return 1.0f/(1.0f+__expf(-x)); }
static __device__ __forceinline__ float tanh_f(float x){
  float a = fabsf(x);
  float e = __expf(2.0f*a);
  float t = 1.0f - 2.0f/(e+1.0f);
  return x >= 0.0f ? t : -t;
}
static __device__ __forceinline__ unsigned short f2bf(float f){
  union { float f; unsigned int u; } v; v.f = f;
  unsigned int u = v.u;
  return (unsigned short)((u + 0x7fffu + ((u>>16)&1u)) >> 16);   // RNE
}

// Poll 16 chunks (16B each) of this thread's h row portion straight from the LLC.
// Freshness = no dword equals SENT. The poll IS the data load (zero extra RTs).
static __device__ __forceinline__ void poll_h(const unsigned long long* h64,
                                              unsigned long long hv[32]){
  unsigned int ok = 0;
  for (int rounds = 0; ok != 0xFFFFu && rounds < POLL_MAX; ++rounds){
    #pragma unroll
    for (int kt=0; kt<16; kt++) if (!(ok & (1u<<kt))){
      hv[2*kt]   = __hip_atomic_load(h64 + kt*8 + 0, __ATOMIC_RELAXED, AGENT);
      hv[2*kt+1] = __hip_atomic_load(h64 + kt*8 + 1, __ATOMIC_RELAXED, AGENT);
    }
    #pragma unroll
    for (int kt=0; kt<16; kt++) if (!(ok & (1u<<kt))){
      unsigned int a = (unsigned int)hv[2*kt],   b = (unsigned int)(hv[2*kt]>>32);
      unsigned int c = (unsigned int)hv[2*kt+1], d = (unsigned int)(hv[2*kt+1]>>32);
      if (a!=SENT && b!=SENT && c!=SENT && d!=SENT) ok |= 1u<<kt;
    }
  }
}

// Clock-keeper v3: FMA burst (SCLK) + HBM/LLC streaming reads (FCLK/UCLK) on idle
// CUs. Each block walks a disjoint 2MB window of a large read-only region —
// coalesced, no hotspot. t0-only done poll, exit via volatile LDS. Cap ~18 ms.
static __device__ __forceinline__ void keeper(const unsigned int* done, unsigned int target,
                                              const float4* __restrict__ sbase, size_t n4){
  volatile __shared__ unsigned int quit;
  if (threadIdx.x == 0) quit = 0u;
  __syncthreads();
  float a = 0.5f + 1e-6f*(float)(threadIdx.x & 63);
  int nt = blockDim.x;
  size_t window = (size_t)256*nt + 1024;
  size_t pos = (((size_t)blockIdx.x * 2654435761u) % (n4 - window));
  for (int it = 0; it < 24000; ++it){
    float4 v = sbase[pos + (size_t)(it & 255)*nt + threadIdx.x];   // 4-8 KB/block/iter
    asm volatile("" :: "v"(v.x), "v"(v.y));    // keep live (rule #17)
    #pragma unroll 4
    for (int k=0;k<256;k++) a = __builtin_fmaf(a, 1.0000001f, 1e-9f);
    asm volatile("" :: "v"(a));
    __builtin_amdgcn_s_sleep(8);               // pace to ~2 TB/s aggregate
    if (threadIdx.x == 0 && (it & 3) == 0 &&
        __hip_atomic_load(done, __ATOMIC_RELAXED, AGENT) >= target) quit = 1u;
    if (quit) break;
  }
}

// ---------------- small converters ----------------
__global__ void k_conv(const float* __restrict__ src, unsigned short* __restrict__ dst, int n){
  int i = blockIdx.x*256 + threadIdx.x;
  if (i < n) dst[i] = f2bf(src[i]);
}
__global__ void k_conv_pad(const float* __restrict__ src, unsigned short* __restrict__ dst,
                           int rows, int ks, int kd){
  int i = blockIdx.x*256 + threadIdx.x;
  int r = i / kd, c = i % kd;
  if (r < rows) dst[i] = (c < ks) ? f2bf(src[r*ks + c]) : (unsigned short)0;
}
__global__ void k_sentinel(float* __restrict__ out, int n){
  int i = blockIdx.x*256 + threadIdx.x;
  if (i < n) out[i] = 1234.5f;
}

// x: [64][69][1000] f32  ->  xT: [(t*64+b)][96] bf16
__global__ void k_xpose(const float* __restrict__ x, unsigned short* __restrict__ xT){
  int b = blockIdx.x & 63, tt = blockIdx.x >> 6;
  int t = tt*64 + threadIdx.x;
  if (t >= T_LEN) return;
  unsigned int* dst = (unsigned int*)(xT + (size_t)(t*64+b)*KIN_P);
  #pragma unroll
  for (int i=0;i<48;i++){
    int k0 = 2*i, k1 = 2*i+1;
    unsigned int lo = (k0<KIN) ? f2bf(x[((size_t)b*KIN + k0)*T_LEN + t]) : 0u;
    unsigned int hi = (k1<KIN) ? f2bf(x[((size_t)b*KIN + k1)*T_LEN + t]) : 0u;
    dst[i] = lo | (hi<<16);
  }
}

// ---------------- layer 0: fused input-proj + bidirectional recurrence ----------------
// blocks 0..31: scan (dir = bid/16, slice = bid%16); blocks 32..255: clock-keepers.
#define NB_B 16
__launch_bounds__(512)
__global__ void k_gru0(const unsigned short* __restrict__ xT,
                       const unsigned short* __restrict__ whh0,
                       const unsigned short* __restrict__ wih0,
                       const float* __restrict__ bih_f, const float* __restrict__ bhh_f,
                       const float* __restrict__ bih_b, const float* __restrict__ bhh_b,
                       unsigned short* __restrict__ l0out,
                       unsigned int* __restrict__ hbuf,   // [2][3][64][256] dwords
                       unsigned int* __restrict__ done)
{
  int bid = blockIdx.x;
  if (bid >= 32){ keeper(done, 32u, (const float4*)l0out, (size_t)8192000); return; }
  int dir = bid / NB_B;
  int n   = bid % NB_B;
  int j0  = n*32;
  int tid = threadIdx.x;
  int w = tid>>6, l = tid&63;
  int m0  = (w & 3) * 16;
  int h16 = w >> 2;
  int lj = l & 15, lg = l >> 4;

  __shared__ unsigned char lds[96*1024 + 96*192];
  unsigned char* whh_lds = lds;
  unsigned char* wih_lds = lds + 96*1024;
  const unsigned short* whh_g = whh0 + (size_t)dir*G3*HDIM;
  const unsigned short* wih_g = wih0 + (size_t)dir*G3*KIN_P;

  for (int c = tid; c < 96*64; c += 512){
    int lr = c >> 6, c16 = c & 63;
    int g = lr >> 5, jl = lr & 31;
    int gr = g*512 + j0 + jl;
    uint4 v = *(const uint4*)(whh_g + (size_t)gr*HDIM + c16*8);
    *(uint4*)(whh_lds + lr*1024 + ((c16*16) ^ ((lr&7)<<4))) = v;
  }
  for (int c = tid; c < 96*12; c += 512){
    int lr = c / 12, c16 = c % 12;
    int g = lr >> 5, jl = lr & 31;
    int gr = g*512 + j0 + jl;
    uint4 v = *(const uint4*)(wih_g + (size_t)gr*KIN_P + c16*8);
    *(uint4*)(wih_lds + lr*192 + ((c16*16) ^ ((lr&3)<<4))) = v;
  }
  __syncthreads();

  int jl_mine = h16*16 + lj;
  int jg = j0 + jl_mine;
  const float* bih = dir ? bih_b : bih_f;
  const float* bhh = dir ? bhh_b : bhh_f;
  float brz = bih[jg] + bhh[jg];
  float bzz = bih[512+jg] + bhh[512+jg];
  float bxn = bih[1024+jg];
  float bhn = bhh[1024+jg];
  float hreg[4] = {0.f,0.f,0.f,0.f};
  unsigned int* hb = hbuf + (size_t)dir*3*64*256;

  for (int ts = 0; ts < T_LEN; ts++){
    int t = dir ? (T_LEN-1-ts) : ts;
    int s_r = ts % 3, s_w = (ts+1) % 3, s_s = (ts+2) % 3;
    f32x4 aR={0.f,0.f,0.f,0.f}, aZ={0.f,0.f,0.f,0.f}, aXN={0.f,0.f,0.f,0.f}, aHN={0.f,0.f,0.f,0.f};

    // input-projection (independent of h)
    const unsigned short* arow = xT + (size_t)(t*64 + m0 + lj)*KIN_P + lg*8;
    #pragma unroll
    for (int kt=0; kt<3; kt++){
      short8 a = *(const short8*)(arow + kt*32);
      int lr0 = jl_mine, lr1 = 32 + jl_mine, lr2 = 64 + jl_mine;
      int co = kt*64 + lg*16;
      short8 b0 = *(const short8*)(wih_lds + lr0*192 + (co ^ ((lr0&3)<<4)));
      short8 b1 = *(const short8*)(wih_lds + lr1*192 + (co ^ ((lr1&3)<<4)));
      short8 b2 = *(const short8*)(wih_lds + lr2*192 + (co ^ ((lr2&3)<<4)));
      aR  = MFMA(a, b0, aR);
      aZ  = MFMA(a, b1, aZ);
      aXN = MFMA(a, b2, aXN);
    }

    // poll h(ts) directly (self-announcing data; ts=0 slot holds zeros = fresh)
    unsigned long long hv[32];
    const unsigned long long* h64 = (const unsigned long long*)(hb + s_r*64*256)
        + ((((m0+lj)*256) + lg*4) >> 1);
    poll_h(h64, hv);

    #pragma unroll
    for (int kt=0; kt<16; kt++){
      union { unsigned long long u[2]; short8 s; } cv;
      cv.u[0] = hv[2*kt]; cv.u[1] = hv[2*kt+1];
      int lr0 = jl_mine, lr1 = 32 + jl_mine, lr2 = 64 + jl_mine;
      int co = kt*64 + lg*16;
      short8 b0 = *(const short8*)(whh_lds + lr0*1024 + (co ^ ((lr0&7)<<4)));
      short8 b1 = *(const short8*)(whh_lds + lr1*1024 + (co ^ ((lr1&7)<<4)));
      short8 b2 = *(const short8*)(whh_lds + lr2*1024 + (co ^ ((lr2&7)<<4)));
      aR  = MFMA(cv.s, b0, aR);
      aZ  = MFMA(cv.s, b1, aZ);
      aHN = MFMA(cv.s, b2, aHN);
    }

    float hnew[4];
    #pragma unroll
    for (int i=0;i<4;i++){
      float r = sigm(aR[i] + brz);
      float z = sigm(aZ[i] + bzz);
      float nn = tanh_f(aXN[i] + bxn + r*(aHN[i] + bhn));
      hnew[i] = (1.0f - z)*nn + z*hreg[i];
      hreg[i] = hnew[i];
    }

    if (ts < T_LEN-1){
      unsigned int packed[4];
      #pragma unroll
      for (int i=0;i<4;i++){
        unsigned short mybf = f2bf(hnew[i]);
        unsigned short ot = (unsigned short)__shfl_xor((int)mybf, 1, 64);
        packed[i] = (unsigned int)mybf | ((unsigned int)ot << 16);
      }
      if ((l & 1) == 0){
        unsigned int* hs = hb + s_s*64*256;
        unsigned int* hw = hb + s_w*64*256;
        #pragma unroll
        for (int i=0;i<4;i++){
          int b = m0 + lg*4 + i;
          __hip_atomic_store(hs + b*256 + (jg>>1), SENT, __ATOMIC_RELAXED, AGENT);
          __hip_atomic_store(hw + b*256 + (jg>>1), packed[i], __ATOMIC_RELAXED, AGENT);
        }
      }
    }

    #pragma unroll
    for (int i=0;i<4;i++){
      int b = m0 + lg*4 + i;
      l0out[(size_t)(t*64+b)*1024 + dir*512 + jg] = f2bf(hnew[i]);
    }
  }
  if (tid == 0) __hip_atomic_fetch_add(done, 1u, __ATOMIC_RELAXED, AGENT);
}

// ---------------- layer 1 ----------------
// blocks 0..31: fwd scan; 32..63: bwd single-step; 64..255: clock-keepers.
__launch_bounds__(256)
__global__ void k_gru1(const unsigned short* __restrict__ l0out,
                       const unsigned short* __restrict__ wih1,
                       const unsigned short* __restrict__ whh1f,
                       const float* __restrict__ bih_f, const float* __restrict__ bhh_f,
                       const float* __restrict__ bih_b, const float* __restrict__ bhh_b,
                       float* __restrict__ l1cat,
                       unsigned int* __restrict__ hbuf,   // [3][64][256] dwords
                       unsigned int* __restrict__ done)
{
  int bid = blockIdx.x;
  if (bid >= 64){ keeper(done, 32u, (const float4*)l0out, (size_t)8192000); return; }
  int bwd = bid >= 32;
  int n = bwd ? bid - 32 : bid;
  int j0 = n*16;
  int tid = threadIdx.x;
  int w = tid>>6, l = tid&63;
  int m0 = w*16, lj = l&15, lg = l>>4;

  __shared__ unsigned char lds[48*2048 + 48*1024];
  unsigned char* wih_lds = lds;
  unsigned char* whh_lds = lds + 48*2048;
  const unsigned short* wih_g = wih1 + (bwd ? (size_t)G3*1024 : 0);

  for (int c = tid; c < 48*128; c += 256){
    int lr = c >> 7, c16 = c & 127;
    int g = lr >> 4, jl = lr & 15;
    int gr = g*512 + j0 + jl;
    uint4 v = *(const uint4*)(wih_g + (size_t)gr*1024 + c16*8);
    *(uint4*)(wih_lds + lr*2048 + ((c16*16) ^ ((lr&7)<<4))) = v;
  }
  if (!bwd){
    for (int c = tid; c < 48*64; c += 256){
      int lr = c >> 6, c16 = c & 63;
      int g = lr >> 4, jl = lr & 15;
      int gr = g*512 + j0 + jl;
      uint4 v = *(const uint4*)(whh1f + (size_t)gr*HDIM + c16*8);
      *(uint4*)(whh_lds + lr*1024 + ((c16*16) ^ ((lr&7)<<4))) = v;
    }
  }
  __syncthreads();

  int jg = j0 + lj;
  const float* bih = bwd ? bih_b : bih_f;
  const float* bhh = bwd ? bhh_b : bhh_f;
  float brz = bih[jg] + bhh[jg];
  float bzz = bih[512+jg] + bhh[512+jg];
  float bxn = bih[1024+jg];
  float bhn = bhh[1024+jg];

  if (bwd){
    int t = T_LEN-1;
    f32x4 aR={0.f,0.f,0.f,0.f}, aZ={0.f,0.f,0.f,0.f}, aXN={0.f,0.f,0.f,0.f};
    const unsigned short* arow = l0out + (size_t)(t*64 + m0 + lj)*1024 + lg*8;
    #pragma unroll 8
    for (int kt=0; kt<32; kt++){
      short8 a = *(const short8*)(arow + kt*32);
      int lr0 = lj, lr1 = 16+lj, lr2 = 32+lj;
      int co = kt*64 + lg*16;
      short8 b0 = *(const short8*)(wih_lds + lr0*2048 + (co ^ ((lr0&7)<<4)));
      short8 b1 = *(const short8*)(wih_lds + lr1*2048 + (co ^ ((lr1&7)<<4)));
      short8 b2 = *(const short8*)(wih_lds + lr2*2048 + (co ^ ((lr2&7)<<4)));
      aR = MFMA(a,b0,aR); aZ = MFMA(a,b1,aZ); aXN = MFMA(a,b2,aXN);
    }
    #pragma unroll
    for (int i=0;i<4;i++){
      float r = sigm(aR[i] + brz);
      float z = sigm(aZ[i] + bzz);
      float nn = tanh_f(aXN[i] + bxn + r*bhn);
      l1cat[(size_t)(m0 + lg*4 + i)*1024 + 512 + jg] = (1.0f - z)*nn;
    }
    return;
  }

  float hreg[4] = {0.f,0.f,0.f,0.f};
  for (int ts = 0; ts < T_LEN; ts++){
    int s_r = ts % 3, s_w = (ts+1) % 3, s_s = (ts+2) % 3;
    f32x4 aR={0.f,0.f,0.f,0.f}, aZ={0.f,0.f,0.f,0.f}, aXN={0.f,0.f,0.f,0.f}, aHN={0.f,0.f,0.f,0.f};
    const unsigned short* arow = l0out + (size_t)(ts*64 + m0 + lj)*1024 + lg*8;
    #pragma unroll 8
    for (int kt=0; kt<32; kt++){
      short8 a = *(const short8*)(arow + kt*32);
      int lr0 = lj, lr1 = 16+lj, lr2 = 32+lj;
      int co = kt*64 + lg*16;
      short8 b0 = *(const short8*)(wih_lds + lr0*2048 + (co ^ ((lr0&7)<<4)));
      short8 b1 = *(const short8*)(wih_lds + lr1*2048 + (co ^ ((lr1&7)<<4)));
      short8 b2 = *(const short8*)(wih_lds + lr2*2048 + (co ^ ((lr2&7)<<4)));
      aR = MFMA(a,b0,aR); aZ = MFMA(a,b1,aZ); aXN = MFMA(a,b2,aXN);
    }

    unsigned long long hv[32];
    const unsigned long long* h64 = (const unsigned long long*)(hbuf + s_r*64*256)
        + ((((m0+lj)*256) + lg*4) >> 1);
    poll_h(h64, hv);

    #pragma unroll
    for (int kt=0; kt<16; kt++){
      union { unsigned long long u[2]; short8 s; } cv;
      cv.u[0] = hv[2*kt]; cv.u[1] = hv[2*kt+1];
      int lr0 = lj, lr1 = 16+lj, lr2 = 32+lj;
      int co = kt*64 + lg*16;
      short8 b0 = *(const short8*)(whh_lds + lr0*1024 + (co ^ ((lr0&7)<<4)));
      short8 b1 = *(const short8*)(whh_lds + lr1*1024 + (co ^ ((lr1&7)<<4)));
      short8 b2 = *(const short8*)(whh_lds + lr2*1024 + (co ^ ((lr2&7)<<4)));
      aR = MFMA(cv.s,b0,aR); aZ = MFMA(cv.s,b1,aZ); aHN = MFMA(cv.s,b2,aHN);
    }
    float hnew[4];
    #pragma unroll
    for (int i=0;i<4;i++){
      float r = sigm(aR[i] + brz);
      float z = sigm(aZ[i] + bzz);
      float nn = tanh_f(aXN[i] + bxn + r*(aHN[i] + bhn));
      hnew[i] = (1.0f - z)*nn + z*hreg[i];
      hreg[i] = hnew[i];
    }
    if (ts < T_LEN-1){
      unsigned int packed[4];
      #pragma unroll
      for (int i=0;i<4;i++){
        unsigned short mybf = f2bf(hnew[i]);
        unsigned short ot = (unsigned short)__shfl_xor((int)mybf, 1, 64);
        packed[i] = (unsigned int)mybf | ((unsigned int)ot << 16);
      }
      if ((l & 1) == 0){
        unsigned int* hs = hbuf + s_s*64*256;
        unsigned int* hw = hbuf + s_w*64*256;
        #pragma unroll
        for (int i=0;i<4;i++){
          int b = m0 + lg*4 + i;
          __hip_atomic_store(hs + b*256 + (jg>>1), SENT, __ATOMIC_RELAXED, AGENT);
          __hip_atomic_store(hw + b*256 + (jg>>1), packed[i], __ATOMIC_RELAXED, AGENT);
        }
      }
    } else {
      #pragma unroll
      for (int i=0;i<4;i++)
        l1cat[(size_t)(m0 + lg*4 + i)*1024 + jg] = hnew[i];
    }
  }
  if (tid == 0) __hip_atomic_fetch_add(done, 1u, __ATOMIC_RELAXED, AGENT);
}

// ---------------- final FC ----------------
__global__ void k_fc(const float* __restrict__ l1cat, const float* __restrict__ fcw,
                     const float* __restrict__ fcb, float* __restrict__ out){
  int idx = blockIdx.x*256 + threadIdx.x;
  if (idx >= 64*12) return;
  int b = idx / 12, o = idx % 12;
  float s = fcb[o];
  for (int k=0;k<1024;k++) s += l1cat[b*1024+k]*fcw[o*1024+k];
  out[idx] = s;
}

extern "C" void kernel_launch(void* const* d_in, const int* in_sizes, int n_in,
                              void* d_out, int out_size, void* d_ws, size_t ws_size,
                              hipStream_t stream){
  const float* x     = (const float*)d_in[0];
  const float* wih0f = (const float*)d_in[1];
  const float* whh0f = (const float*)d_in[2];
  const float* bih0f = (const float*)d_in[3];
  const float* bhh0f = (const float*)d_in[4];
  const float* wih0b = (const float*)d_in[5];
  const float* whh0b = (const float*)d_in[6];
  const float* bih0b = (const float*)d_in[7];
  const float* bhh0b = (const float*)d_in[8];
  const float* wih1f = (const float*)d_in[9];
  const float* whh1f = (const float*)d_in[10];
  const float* bih1f = (const float*)d_in[11];
  const float* bhh1f = (const float*)d_in[12];
  const float* wih1b = (const float*)d_in[13];
  const float* bih1b = (const float*)d_in[15];
  const float* bhh1b = (const float*)d_in[16];
  const float* fcw   = (const float*)d_in[17];
  const float* fcb   = (const float*)d_in[18];

  const size_t SLOT = (size_t)64*256*4;   // 64 KB per ring slot

  char* ws = (char*)d_ws;
  size_t off = 0;
  auto alloc = [&](size_t bytes)->void*{ void* p = ws + off; off = (off + bytes + 255) & ~(size_t)255; return p; };
  unsigned short* xT    = (unsigned short*)alloc((size_t)64000*96*2);
  unsigned short* whh0c = (unsigned short*)alloc((size_t)2*1536*512*2);
  unsigned short* wih0c = (unsigned short*)alloc((size_t)2*1536*96*2);
  unsigned short* wih1c = (unsigned short*)alloc((size_t)2*1536*1024*2);
  unsigned short* whh1c = (unsigned short*)alloc((size_t)1536*512*2);
  unsigned short* l0out = (unsigned short*)alloc((size_t)64000*1024*2);
  unsigned int*   hbB   = (unsigned int*)alloc((size_t)2*3*SLOT);   // [2][3][64][256]
  unsigned int*   hbD   = (unsigned int*)alloc((size_t)3*SLOT);     // [3][64][256]
  float*          l1cat = (float*)alloc((size_t)64*1024*4);
  unsigned int*   sync  = (unsigned int*)alloc(256);                // done0 | done1

  if (off > ws_size){
    k_sentinel<<<(out_size+255)/256,256,0,stream>>>((float*)d_out, out_size);
    return;
  }

  // ring init: slot 0 = zeros (h0 = 0), slots 1..2 = 0xFF sentinel bytes
  for (int d = 0; d < 2; d++){
    char* base = (char*)hbB + (size_t)d*3*SLOT;
    hipMemsetAsync(base, 0, SLOT, stream);
    hipMemsetAsync(base + SLOT, 0xFF, 2*SLOT, stream);
  }
  hipMemsetAsync(hbD, 0, SLOT, stream);
  hipMemsetAsync((char*)hbD + SLOT, 0xFF, 2*SLOT, stream);
  hipMemsetAsync(sync, 0, 256, stream);

  k_conv<<<3072,256,0,stream>>>(whh0f, whh0c, 786432);
  k_conv<<<3072,256,0,stream>>>(whh0b, whh0c+786432, 786432);
  k_conv_pad<<<576,256,0,stream>>>(wih0f, wih0c, 1536, 69, 96);
  k_conv_pad<<<576,256,0,stream>>>(wih0b, wih0c+1536*96, 1536, 69, 96);
  k_conv<<<6144,256,0,stream>>>(wih1f, wih1c, 1572864);
  k_conv<<<6144,256,0,stream>>>(wih1b, wih1c+1572864, 1572864);
  k_conv<<<3072,256,0,stream>>>(whh1f, whh1c, 786432);
  k_xpose<<<1024,64,0,stream>>>(x, xT);

  k_gru0<<<256,512,0,stream>>>(xT, whh0c, wih0c, bih0f,bhh0f,bih0b,bhh0b, l0out, hbB, sync);
  k_gru1<<<256,256,0,stream>>>(l0out, wih1c, whh1c, bih1f,bhh1f,bih1b,bhh1b, l1cat, hbD, sync+32);
  k_fc<<<3,256,0,stream>>>(l1cat, fcw, fcb, (float*)d_out);
}